// Round 3
// baseline (505.004 us; speedup 1.0000x reference)
//
#include <hip/hip_runtime.h>
#include <hip/hip_bf16.h>

#define NN   100000
#define KNB  32
#define DIN  256
#define DOUT 128

typedef __attribute__((ext_vector_type(8))) short short8;    // 8 x bf16
typedef __attribute__((ext_vector_type(4))) float f32x4;     // 4 x f32
typedef __attribute__((ext_vector_type(4))) unsigned u32x4;  // 16 B
typedef __attribute__((ext_vector_type(2))) int i32x2;       // 8 B

// v_cvt_pk_bf16_f32: packs 2 f32 -> 2 bf16 (RTNE) in one VALU op.
// No builtin on gfx950 (m240) -> inline asm.
__device__ __forceinline__ unsigned pk2(float a, float b) {
    unsigned r;
    asm("v_cvt_pk_bf16_f32 %0, %1, %2" : "=v"(r) : "v"(a), "v"(b));
    return r;
}

__device__ __forceinline__ short8 cvt8(f32x4 a, f32x4 b) {
    u32x4 t;
    t[0] = pk2(a[0], a[1]);
    t[1] = pk2(a[2], a[3]);
    t[2] = pk2(b[0], b[1]);
    t[3] = pk2(b[2], b[3]);
    return __builtin_bit_cast(short8, t);
}

// ---------------------------------------------------------------------------
// Kernel 0: W [DIN][DOUT] f32  ->  Wt [DOUT][DIN] bf16 (transposed + converted)
// ---------------------------------------------------------------------------
__global__ void wt_conv(const float* __restrict__ W, unsigned short* __restrict__ Wt) {
    int t = blockIdx.x * 256 + threadIdx.x;   // 0 .. 32767
    int d = t >> 8;                           // dout
    int k = t & 255;                          // din
    float v = W[(size_t)k * DOUT + d];
    Wt[t] = (unsigned short)(pk2(v, v) & 0xffffu);
}

// ---------------------------------------------------------------------------
// Kernel 1: h = relu(feats @ W + b), stored bf16.
// Operand-swapped MFMA: A = Wt (M = DOUT), B = feats^T (N = nodes).
// Wave handles 32 nodes x 128 douts. Wt (64 KB) streams from L1/L2.
// ---------------------------------------------------------------------------
__global__ __launch_bounds__(256) void gemm_relu(
        const float* __restrict__ feats, const unsigned short* __restrict__ Wt,
        const float* __restrict__ bias, unsigned short* __restrict__ h) {
    const int lane = threadIdx.x & 63;
    const int wid  = threadIdx.x >> 6;
    const int l16  = lane & 15;
    const int lq   = lane >> 4;
    const int nodeBase = blockIdx.x * 128 + wid * 32;

    f32x4 acc[8][2];
    #pragma unroll
    for (int mf = 0; mf < 8; ++mf) { acc[mf][0] = (f32x4)0.f; acc[mf][1] = (f32x4)0.f; }

    int n0 = nodeBase + l16;
    int n1 = nodeBase + 16 + l16;
    int n0c = n0 < NN ? n0 : NN - 1;          // clamp loads; stores are predicated
    int n1c = n1 < NN ? n1 : NN - 1;
    const float* f0p = feats + (size_t)n0c * DIN + lq * 8;
    const float* f1p = feats + (size_t)n1c * DIN + lq * 8;
    const unsigned short* wp = Wt + l16 * DIN + lq * 8;

    #pragma unroll
    for (int ks = 0; ks < 8; ++ks) {
        f32x4 a0 = __builtin_nontemporal_load((const f32x4*)(f0p + ks * 32));
        f32x4 a1 = __builtin_nontemporal_load((const f32x4*)(f0p + ks * 32 + 4));
        f32x4 c0 = __builtin_nontemporal_load((const f32x4*)(f1p + ks * 32));
        f32x4 c1 = __builtin_nontemporal_load((const f32x4*)(f1p + ks * 32 + 4));
        short8 bfrag0 = cvt8(a0, a1);
        short8 bfrag1 = cvt8(c0, c1);
        #pragma unroll
        for (int mf = 0; mf < 8; ++mf) {
            short8 a = *(const short8*)(wp + mf * 16 * DIN + ks * 32);
            acc[mf][0] = __builtin_amdgcn_mfma_f32_16x16x32_bf16(a, bfrag0, acc[mf][0], 0, 0, 0);
            acc[mf][1] = __builtin_amdgcn_mfma_f32_16x16x32_bf16(a, bfrag1, acc[mf][1], 0, 0, 0);
        }
    }

    // Epilogue: bias + relu + pack 4 bf16 -> 8 B store.
    // D layout: col (node) = lane&15, row (dout) = (lane>>4)*4 + reg  [m89]
    #pragma unroll
    for (int mf = 0; mf < 8; ++mf) {
        int dbase = mf * 16 + lq * 4;
        f32x4 bv = *(const f32x4*)(bias + dbase);
        #pragma unroll
        for (int nf = 0; nf < 2; ++nf) {
            int node = nodeBase + nf * 16 + l16;
            if (node < NN) {
                f32x4 v = acc[mf][nf];
                float v0 = fmaxf(v[0] + bv[0], 0.f);
                float v1 = fmaxf(v[1] + bv[1], 0.f);
                float v2 = fmaxf(v[2] + bv[2], 0.f);
                float v3 = fmaxf(v[3] + bv[3], 0.f);
                uint2 st = make_uint2(pk2(v0, v1), pk2(v2, v3));
                *(uint2*)(h + (size_t)node * DOUT + dbase) = st;
            }
        }
    }
}

// ---------------------------------------------------------------------------
// Kernel 2: out[n] = mean_k h_bf16[edge[n][k]]
// Quarter-wave (16 lanes) per node, 16 B dwordx4 per lane, 4-deep pipeline.
// nontemporal edge loads / out stores keep L2 free for h.
// ---------------------------------------------------------------------------
__global__ __launch_bounds__(256, 8) void gather_mean(
        const int* __restrict__ edge, const unsigned short* __restrict__ h,
        float* __restrict__ out) {
    const int q = threadIdx.x & 15;
    const int n = blockIdx.x * 16 + (threadIdx.x >> 4);   // 6250*16 == NN exactly

    // lane q holds edge[n][2q], edge[n][2q+1]; k-order permuted (sum invariant)
    i32x2 e2 = __builtin_nontemporal_load((const i32x2*)(edge + n * KNB + q * 2));

    float s0=0,s1=0,s2=0,s3=0,s4=0,s5=0,s6=0,s7=0;
    u32x4 buf[4];

    #define ADDR(k) ((const u32x4*)(h + (size_t)((k) < 16 ? __shfl(e2[0], (k), 16) \
                                                          : __shfl(e2[1], (k) - 16, 16)) * DOUT) + q)
    #pragma unroll
    for (int k = 0; k < 4; ++k) buf[k] = *ADDR(k);

    #pragma unroll
    for (int k = 0; k < KNB; ++k) {
        u32x4 v = buf[k & 3];
        if (k + 4 < KNB) buf[k & 3] = *ADDR(k + 4);
        s0 += __uint_as_float(v[0] << 16);
        s1 += __uint_as_float(v[0] & 0xffff0000u);
        s2 += __uint_as_float(v[1] << 16);
        s3 += __uint_as_float(v[1] & 0xffff0000u);
        s4 += __uint_as_float(v[2] << 16);
        s5 += __uint_as_float(v[2] & 0xffff0000u);
        s6 += __uint_as_float(v[3] << 16);
        s7 += __uint_as_float(v[3] & 0xffff0000u);
    }
    #undef ADDR

    const float sc = 1.f / KNB;
    f32x4 o0 = { s0 * sc, s1 * sc, s2 * sc, s3 * sc };
    f32x4 o1 = { s4 * sc, s5 * sc, s6 * sc, s7 * sc };
    float* op = out + (size_t)n * DOUT + q * 8;
    __builtin_nontemporal_store(o0, (f32x4*)op);
    __builtin_nontemporal_store(o1, (f32x4*)(op + 4));
}

// ---------------------------------------------------------------------------
extern "C" void kernel_launch(void* const* d_in, const int* in_sizes, int n_in,
                              void* d_out, int out_size, void* d_ws, size_t ws_size,
                              hipStream_t stream) {
    const float* feats = (const float*)d_in[0];   // [100000,256] f32
    const int*   edge  = (const int*)d_in[1];     // [100000,32] i32
    const float* W     = (const float*)d_in[2];   // [256,128] f32
    const float* b     = (const float*)d_in[3];   // [128] f32
    float* out = (float*)d_out;                   // [100000,128] f32

    unsigned short* Wt = (unsigned short*)d_ws;                    // 64 KB
    unsigned short* h  = (unsigned short*)((char*)d_ws + 65536);   // 25.6 MB

    wt_conv<<<128, 256, 0, stream>>>(W, Wt);
    gemm_relu<<<(NN + 127) / 128, 256, 0, stream>>>(feats, Wt, b, h);
    gather_mean<<<NN / 16, 256, 0, stream>>>(edge, h, out);
}

// Round 4
// 176.826 us; speedup vs baseline: 2.8559x; 2.8559x over previous
//
#include <hip/hip_runtime.h>
#include <hip/hip_bf16.h>

#define NN   100000
#define KNB  32
#define DIN  256
#define DOUT 128

typedef __attribute__((ext_vector_type(8))) short short8;    // 8 x bf16
typedef __attribute__((ext_vector_type(4))) float f32x4;     // 4 x f32
typedef __attribute__((ext_vector_type(4))) unsigned u32x4;  // 16 B
typedef __attribute__((ext_vector_type(2))) int i32x2;       // 8 B

// v_cvt_pk_bf16_f32: packs 2 f32 -> 2 bf16 (RTNE) in one VALU op.
// No builtin on gfx950 (m240) -> inline asm.
__device__ __forceinline__ unsigned pk2(float a, float b) {
    unsigned r;
    asm("v_cvt_pk_bf16_f32 %0, %1, %2" : "=v"(r) : "v"(a), "v"(b));
    return r;
}

__device__ __forceinline__ short8 cvt8(f32x4 a, f32x4 b) {
    u32x4 t;
    t[0] = pk2(a[0], a[1]);
    t[1] = pk2(a[2], a[3]);
    t[2] = pk2(b[0], b[1]);
    t[3] = pk2(b[2], b[3]);
    return __builtin_bit_cast(short8, t);
}

// ---------------------------------------------------------------------------
// Kernel 0: W [DIN][DOUT] f32  ->  Wt [DOUT][DIN] bf16 (transposed + converted)
// ---------------------------------------------------------------------------
__global__ void wt_conv(const float* __restrict__ W, unsigned short* __restrict__ Wt) {
    int t = blockIdx.x * 256 + threadIdx.x;   // 0 .. 32767
    int d = t >> 8;                           // dout
    int k = t & 255;                          // din
    float v = W[(size_t)k * DOUT + d];
    Wt[t] = (unsigned short)(pk2(v, v) & 0xffffu);
}

// ---------------------------------------------------------------------------
// Kernel 1: h = relu(feats @ W + b), stored bf16.
// Operand-swapped MFMA: A = Wt (M = DOUT), B = feats^T (N = nodes).
// Wave handles 32 nodes x 128 douts. Wt (64 KB) streams from L1/L2.
// ---------------------------------------------------------------------------
__global__ __launch_bounds__(256) void gemm_relu(
        const float* __restrict__ feats, const unsigned short* __restrict__ Wt,
        const float* __restrict__ bias, unsigned short* __restrict__ h) {
    const int lane = threadIdx.x & 63;
    const int wid  = threadIdx.x >> 6;
    const int l16  = lane & 15;
    const int lq   = lane >> 4;
    const int nodeBase = blockIdx.x * 128 + wid * 32;

    f32x4 acc[8][2];
    #pragma unroll
    for (int mf = 0; mf < 8; ++mf) { acc[mf][0] = (f32x4)0.f; acc[mf][1] = (f32x4)0.f; }

    int n0 = nodeBase + l16;
    int n1 = nodeBase + 16 + l16;
    int n0c = n0 < NN ? n0 : NN - 1;          // clamp loads; stores are predicated
    int n1c = n1 < NN ? n1 : NN - 1;
    const float* f0p = feats + (size_t)n0c * DIN + lq * 8;
    const float* f1p = feats + (size_t)n1c * DIN + lq * 8;
    const unsigned short* wp = Wt + l16 * DIN + lq * 8;

    #pragma unroll
    for (int ks = 0; ks < 8; ++ks) {
        f32x4 a0 = __builtin_nontemporal_load((const f32x4*)(f0p + ks * 32));
        f32x4 a1 = __builtin_nontemporal_load((const f32x4*)(f0p + ks * 32 + 4));
        f32x4 c0 = __builtin_nontemporal_load((const f32x4*)(f1p + ks * 32));
        f32x4 c1 = __builtin_nontemporal_load((const f32x4*)(f1p + ks * 32 + 4));
        short8 bfrag0 = cvt8(a0, a1);
        short8 bfrag1 = cvt8(c0, c1);
        #pragma unroll
        for (int mf = 0; mf < 8; ++mf) {
            short8 a = *(const short8*)(wp + mf * 16 * DIN + ks * 32);
            acc[mf][0] = __builtin_amdgcn_mfma_f32_16x16x32_bf16(a, bfrag0, acc[mf][0], 0, 0, 0);
            acc[mf][1] = __builtin_amdgcn_mfma_f32_16x16x32_bf16(a, bfrag1, acc[mf][1], 0, 0, 0);
        }
    }

    // Epilogue: bias + relu + pack 4 bf16 -> 8 B store.
    // D layout: col (node) = lane&15, row (dout) = (lane>>4)*4 + reg  [m89]
    #pragma unroll
    for (int mf = 0; mf < 8; ++mf) {
        int dbase = mf * 16 + lq * 4;
        f32x4 bv = *(const f32x4*)(bias + dbase);
        #pragma unroll
        for (int nf = 0; nf < 2; ++nf) {
            int node = nodeBase + nf * 16 + l16;
            if (node < NN) {
                f32x4 v = acc[mf][nf];
                float v0 = fmaxf(v[0] + bv[0], 0.f);
                float v1 = fmaxf(v[1] + bv[1], 0.f);
                float v2 = fmaxf(v[2] + bv[2], 0.f);
                float v3 = fmaxf(v[3] + bv[3], 0.f);
                uint2 st = make_uint2(pk2(v0, v1), pk2(v2, v3));
                *(uint2*)(h + (size_t)node * DOUT + dbase) = st;
            }
        }
    }
}

// ---------------------------------------------------------------------------
// Kernel 2: out[n] = mean_k h_bf16[edge[n][k]]
// Quarter-wave (16 lanes) per node, 16 B dwordx4 per lane.
// 8-deep software pipeline with NAMED registers only (R3 post-mortem:
// array-indexed buffers spilled to scratch -> 730 MB of scratch traffic).
// ---------------------------------------------------------------------------
__global__ __launch_bounds__(256) void gather_mean(
        const int* __restrict__ edge, const unsigned short* __restrict__ h,
        float* __restrict__ out) {
    const int q = threadIdx.x & 15;
    const int n = blockIdx.x * 16 + (threadIdx.x >> 4);   // 6250*16 == NN exactly

    // lane q holds edge[n][2q], edge[n][2q+1]; k-order within a node is a
    // permutation of the reference order (sum is invariant).
    i32x2 e2 = __builtin_nontemporal_load((const i32x2*)(edge + n * KNB + q * 2));

    float s0=0,s1=0,s2=0,s3=0,s4=0,s5=0,s6=0,s7=0;

    #define ROW(k) ((size_t)((k) < 16 ? __shfl(e2[0], (k), 16) \
                                      : __shfl(e2[1], (k) - 16, 16)) * DOUT)
    #define LD(k)  (*(const u32x4*)(h + ROW(k) + q * 8))
    #define ACC(v) do { \
        s0 += __uint_as_float((v)[0] << 16); \
        s1 += __uint_as_float((v)[0] & 0xffff0000u); \
        s2 += __uint_as_float((v)[1] << 16); \
        s3 += __uint_as_float((v)[1] & 0xffff0000u); \
        s4 += __uint_as_float((v)[2] << 16); \
        s5 += __uint_as_float((v)[2] & 0xffff0000u); \
        s6 += __uint_as_float((v)[3] << 16); \
        s7 += __uint_as_float((v)[3] & 0xffff0000u); } while (0)
    #define STEP(k, B) do { u32x4 v_ = (B); \
        if ((k) + 8 < KNB) (B) = LD((k) + 8); \
        ACC(v_); } while (0)

    u32x4 b0 = LD(0), b1 = LD(1), b2 = LD(2), b3 = LD(3);
    u32x4 b4 = LD(4), b5 = LD(5), b6 = LD(6), b7 = LD(7);

    STEP( 0, b0); STEP( 1, b1); STEP( 2, b2); STEP( 3, b3);
    STEP( 4, b4); STEP( 5, b5); STEP( 6, b6); STEP( 7, b7);
    STEP( 8, b0); STEP( 9, b1); STEP(10, b2); STEP(11, b3);
    STEP(12, b4); STEP(13, b5); STEP(14, b6); STEP(15, b7);
    STEP(16, b0); STEP(17, b1); STEP(18, b2); STEP(19, b3);
    STEP(20, b4); STEP(21, b5); STEP(22, b6); STEP(23, b7);
    STEP(24, b0); STEP(25, b1); STEP(26, b2); STEP(27, b3);
    STEP(28, b4); STEP(29, b5); STEP(30, b6); STEP(31, b7);

    #undef STEP
    #undef ACC
    #undef LD
    #undef ROW

    const float sc = 1.f / KNB;
    f32x4 o0 = { s0 * sc, s1 * sc, s2 * sc, s3 * sc };
    f32x4 o1 = { s4 * sc, s5 * sc, s6 * sc, s7 * sc };
    float* op = out + (size_t)n * DOUT + q * 8;
    __builtin_nontemporal_store(o0, (f32x4*)op);
    __builtin_nontemporal_store(o1, (f32x4*)(op + 4));
}

// ---------------------------------------------------------------------------
extern "C" void kernel_launch(void* const* d_in, const int* in_sizes, int n_in,
                              void* d_out, int out_size, void* d_ws, size_t ws_size,
                              hipStream_t stream) {
    const float* feats = (const float*)d_in[0];   // [100000,256] f32
    const int*   edge  = (const int*)d_in[1];     // [100000,32] i32
    const float* W     = (const float*)d_in[2];   // [256,128] f32
    const float* b     = (const float*)d_in[3];   // [128] f32
    float* out = (float*)d_out;                   // [100000,128] f32

    unsigned short* Wt = (unsigned short*)d_ws;                    // 64 KB
    unsigned short* h  = (unsigned short*)((char*)d_ws + 65536);   // 25.6 MB

    wt_conv<<<128, 256, 0, stream>>>(W, Wt);
    gemm_relu<<<(NN + 127) / 128, 256, 0, stream>>>(feats, Wt, b, h);
    gather_mean<<<NN / 16, 256, 0, stream>>>(edge, h, out);
}

// Round 5
// 167.551 us; speedup vs baseline: 3.0140x; 1.0554x over previous
//
#include <hip/hip_runtime.h>
#include <hip/hip_bf16.h>

#define NN   100000
#define KNB  32
#define DIN  256
#define DOUT 128

typedef __attribute__((ext_vector_type(8))) short short8;    // 8 x bf16
typedef __attribute__((ext_vector_type(4))) float f32x4;     // 4 x f32
typedef __attribute__((ext_vector_type(4))) unsigned u32x4;  // 16 B
typedef __attribute__((ext_vector_type(2))) int i32x2;       // 8 B

// v_cvt_pk_bf16_f32: packs 2 f32 -> 2 bf16 (RTNE) in one VALU op.
// No builtin on gfx950 (m240) -> inline asm.
__device__ __forceinline__ unsigned pk2(float a, float b) {
    unsigned r;
    asm("v_cvt_pk_bf16_f32 %0, %1, %2" : "=v"(r) : "v"(a), "v"(b));
    return r;
}

__device__ __forceinline__ short8 cvt8(f32x4 a, f32x4 b) {
    u32x4 t;
    t[0] = pk2(a[0], a[1]);
    t[1] = pk2(a[2], a[3]);
    t[2] = pk2(b[0], b[1]);
    t[3] = pk2(b[2], b[3]);
    return __builtin_bit_cast(short8, t);
}

// ---------------------------------------------------------------------------
// Kernel 0: W [DIN][DOUT] f32  ->  Wt [DOUT][DIN] bf16 (transposed + converted)
// ---------------------------------------------------------------------------
__global__ void wt_conv(const float* __restrict__ W, unsigned short* __restrict__ Wt) {
    int t = blockIdx.x * 256 + threadIdx.x;   // 0 .. 32767
    int d = t >> 8;                           // dout
    int k = t & 255;                          // din
    float v = W[(size_t)k * DOUT + d];
    Wt[t] = (unsigned short)(pk2(v, v) & 0xffffu);
}

// ---------------------------------------------------------------------------
// Kernel 1: h = relu(feats @ W + b), stored bf16.
// Operand-swapped MFMA: A = Wt (M = DOUT), B = feats^T (N = nodes).
// ONE WAVE per block, 32 nodes per wave: grid 3125 -> 12.2 blocks/CU (8%
// imbalance vs 33% at 782 blocks). 3125*32 == NN exactly -> no bounds checks.
// feats loads are CACHED (R4 post-mortem: NT loads double-fetched every 64 B
// line because a0/a1 instruction pairs split each line; L1 must merge them).
// ---------------------------------------------------------------------------
__global__ __launch_bounds__(64) void gemm_relu(
        const float* __restrict__ feats, const unsigned short* __restrict__ Wt,
        const float* __restrict__ bias, unsigned short* __restrict__ h) {
    const int lane = threadIdx.x;             // 0..63
    const int l16  = lane & 15;
    const int lq   = lane >> 4;
    const int nodeBase = blockIdx.x * 32;     // 3125 * 32 == 100000

    f32x4 acc[8][2];
    #pragma unroll
    for (int mf = 0; mf < 8; ++mf) { acc[mf][0] = (f32x4)0.f; acc[mf][1] = (f32x4)0.f; }

    const float* f0p = feats + (size_t)(nodeBase + l16) * DIN + lq * 8;
    const float* f1p = f0p + 16 * DIN;
    const unsigned short* wp = Wt + l16 * DIN + lq * 8;

    #pragma unroll
    for (int ks = 0; ks < 8; ++ks) {
        f32x4 a0 = *(const f32x4*)(f0p + ks * 32);
        f32x4 a1 = *(const f32x4*)(f0p + ks * 32 + 4);
        f32x4 c0 = *(const f32x4*)(f1p + ks * 32);
        f32x4 c1 = *(const f32x4*)(f1p + ks * 32 + 4);
        short8 bfrag0 = cvt8(a0, a1);
        short8 bfrag1 = cvt8(c0, c1);
        #pragma unroll
        for (int mf = 0; mf < 8; ++mf) {
            short8 a = *(const short8*)(wp + mf * 16 * DIN + ks * 32);
            acc[mf][0] = __builtin_amdgcn_mfma_f32_16x16x32_bf16(a, bfrag0, acc[mf][0], 0, 0, 0);
            acc[mf][1] = __builtin_amdgcn_mfma_f32_16x16x32_bf16(a, bfrag1, acc[mf][1], 0, 0, 0);
        }
    }

    // Epilogue: bias + relu + pack 4 bf16 -> 8 B store.
    // D layout: col (node) = lane&15, row (dout) = (lane>>4)*4 + reg  [m89]
    #pragma unroll
    for (int mf = 0; mf < 8; ++mf) {
        int dbase = mf * 16 + lq * 4;
        f32x4 bv = *(const f32x4*)(bias + dbase);
        #pragma unroll
        for (int nf = 0; nf < 2; ++nf) {
            int node = nodeBase + nf * 16 + l16;
            f32x4 v = acc[mf][nf];
            float v0 = fmaxf(v[0] + bv[0], 0.f);
            float v1 = fmaxf(v[1] + bv[1], 0.f);
            float v2 = fmaxf(v[2] + bv[2], 0.f);
            float v3 = fmaxf(v[3] + bv[3], 0.f);
            uint2 st = make_uint2(pk2(v0, v1), pk2(v2, v3));
            *(uint2*)(h + (size_t)node * DOUT + dbase) = st;
        }
    }
}

// ---------------------------------------------------------------------------
// Kernel 2: out[n] = mean_k h_bf16[edge[n][k]]
// Quarter-wave (16 lanes) per node, 16 B dwordx4 per lane.
// 8-deep NAMED-register pipeline (R3: array-indexed bufs spilled to scratch).
// NT on edge loads + out stores (single-instruction-per-line streams) keeps
// L2 reserved for h. Fill-side BW-bound at ~3.8 TB/s (R4 counters).
// ---------------------------------------------------------------------------
__global__ __launch_bounds__(256) void gather_mean(
        const int* __restrict__ edge, const unsigned short* __restrict__ h,
        float* __restrict__ out) {
    const int q = threadIdx.x & 15;
    const int n = blockIdx.x * 16 + (threadIdx.x >> 4);   // 6250*16 == NN exactly

    // lane q holds edge[n][2q], edge[n][2q+1]; k-order permuted (sum invariant)
    i32x2 e2 = __builtin_nontemporal_load((const i32x2*)(edge + n * KNB + q * 2));

    float s0=0,s1=0,s2=0,s3=0,s4=0,s5=0,s6=0,s7=0;

    #define ROW(k) ((size_t)((k) < 16 ? __shfl(e2[0], (k), 16) \
                                      : __shfl(e2[1], (k) - 16, 16)) * DOUT)
    #define LD(k)  (*(const u32x4*)(h + ROW(k) + q * 8))
    #define ACC(v) do { \
        s0 += __uint_as_float((v)[0] << 16); \
        s1 += __uint_as_float((v)[0] & 0xffff0000u); \
        s2 += __uint_as_float((v)[1] << 16); \
        s3 += __uint_as_float((v)[1] & 0xffff0000u); \
        s4 += __uint_as_float((v)[2] << 16); \
        s5 += __uint_as_float((v)[2] & 0xffff0000u); \
        s6 += __uint_as_float((v)[3] << 16); \
        s7 += __uint_as_float((v)[3] & 0xffff0000u); } while (0)
    #define STEP(k, B) do { u32x4 v_ = (B); \
        if ((k) + 8 < KNB) (B) = LD((k) + 8); \
        ACC(v_); } while (0)

    u32x4 b0 = LD(0), b1 = LD(1), b2 = LD(2), b3 = LD(3);
    u32x4 b4 = LD(4), b5 = LD(5), b6 = LD(6), b7 = LD(7);

    STEP( 0, b0); STEP( 1, b1); STEP( 2, b2); STEP( 3, b3);
    STEP( 4, b4); STEP( 5, b5); STEP( 6, b6); STEP( 7, b7);
    STEP( 8, b0); STEP( 9, b1); STEP(10, b2); STEP(11, b3);
    STEP(12, b4); STEP(13, b5); STEP(14, b6); STEP(15, b7);
    STEP(16, b0); STEP(17, b1); STEP(18, b2); STEP(19, b3);
    STEP(20, b4); STEP(21, b5); STEP(22, b6); STEP(23, b7);
    STEP(24, b0); STEP(25, b1); STEP(26, b2); STEP(27, b3);
    STEP(28, b4); STEP(29, b5); STEP(30, b6); STEP(31, b7);

    #undef STEP
    #undef ACC
    #undef LD
    #undef ROW

    const float sc = 1.f / KNB;
    f32x4 o0 = { s0 * sc, s1 * sc, s2 * sc, s3 * sc };
    f32x4 o1 = { s4 * sc, s5 * sc, s6 * sc, s7 * sc };
    float* op = out + (size_t)n * DOUT + q * 8;
    __builtin_nontemporal_store(o0, (f32x4*)op);
    __builtin_nontemporal_store(o1, (f32x4*)(op + 4));
}

// ---------------------------------------------------------------------------
extern "C" void kernel_launch(void* const* d_in, const int* in_sizes, int n_in,
                              void* d_out, int out_size, void* d_ws, size_t ws_size,
                              hipStream_t stream) {
    const float* feats = (const float*)d_in[0];   // [100000,256] f32
    const int*   edge  = (const int*)d_in[1];     // [100000,32] i32
    const float* W     = (const float*)d_in[2];   // [256,128] f32
    const float* b     = (const float*)d_in[3];   // [128] f32
    float* out = (float*)d_out;                   // [100000,128] f32

    unsigned short* Wt = (unsigned short*)d_ws;                    // 64 KB
    unsigned short* h  = (unsigned short*)((char*)d_ws + 65536);   // 25.6 MB

    wt_conv<<<128, 256, 0, stream>>>(W, Wt);
    gemm_relu<<<NN / 32, 64, 0, stream>>>(feats, Wt, b, h);
    gather_mean<<<NN / 16, 256, 0, stream>>>(edge, h, out);
}